// Round 1
// baseline (754.471 us; speedup 1.0000x reference)
//
#include <hip/hip_runtime.h>

#define L 50
#define NA 120
#define NB 8
#define NPIX 2500        // 50*50
#define NFREQ 51
#define NFULL 100
#define SPEC 5100        // 100*51
#define ASTEP 0.026179938779914944f  // pi/120

// workspace layout in floats
#define OFF_REC   0                // 8*2*2500        = 40000
#define OFF_LIG   40000            // 8*2*2500        = 40000
#define OFF_ROT   80000            // 120*8*2*2500    = 4800000
#define OFF_F1    4880000          // 16*5100 float2  = 163200 floats
#define OFF_P     5043200          // 960*5100 float2 = 9792000 floats
#define OFF_PVAL  14835200         // 960
#define OFF_PIDX  14836160         // 960 ints

// ---------------- conv 3x3 (SAME, cross-correlation) + bias; ligand channels
// combined with scorer weights (linearity: rotate/FFT commute with combine) --
__global__ __launch_bounds__(256) void k_conv(
    const float* __restrict__ rec, const float* __restrict__ lig,
    const float* __restrict__ cw, const float* __restrict__ cb,
    const float* __restrict__ sw,
    float* __restrict__ rec_feat, float* __restrict__ lig_comb) {
  int t = blockIdx.x * blockDim.x + threadIdx.x;
  if (t >= NB * NPIX) return;
  int b = t / NPIX, p = t % NPIX;
  int i = p / L, j = p % L;
  float r0 = cb[0], r1 = cb[1], l0 = cb[0], l1 = cb[1];
  for (int di = 0; di < 3; ++di) {
    int ii = i + di - 1;
    if (ii < 0 || ii >= L) continue;
    for (int dj = 0; dj < 3; ++dj) {
      int jj = j + dj - 1;
      if (jj < 0 || jj >= L) continue;
      float w0 = cw[di * 3 + dj], w1 = cw[9 + di * 3 + dj];
      float xv = rec[b * NPIX + ii * L + jj];
      float yv = lig[b * NPIX + ii * L + jj];
      r0 += w0 * xv; r1 += w1 * xv;
      l0 += w0 * yv; l1 += w1 * yv;
    }
  }
  rec_feat[(b * 2 + 0) * NPIX + p] = r0;
  rec_feat[(b * 2 + 1) * NPIX + p] = r1;
  lig_comb[(b * 2 + 0) * NPIX + p] = sw[0] * l0 + sw[1] * l1;
  lig_comb[(b * 2 + 1) * NPIX + p] = sw[2] * l0 + sw[3] * l1;
}

// ---------------- bilinear rotation, matches jnp grid semantics ------------
__global__ __launch_bounds__(256) void k_rotate(
    const float* __restrict__ lig_comb, float* __restrict__ rot) {
  int t = blockIdx.x * blockDim.x + threadIdx.x;
  if (t >= NA * NB * 2 * NPIX) return;
  int p = t % NPIX;
  int f = (t / NPIX) & 1;
  int b = (t / (2 * NPIX)) % NB;
  int a = t / (NB * 2 * NPIX);
  int i = p / L, j = p % L;
  float sn, cs;
  sincosf(a * ASTEP, &sn, &cs);
  float gx = -1.0f + j * (2.0f / 49.0f);
  float gy = -1.0f + i * (2.0f / 49.0f);
  float xr = cs * gx + sn * gy;
  float yr = -sn * gx + cs * gy;
  float ix = (xr + 1.0f) * 0.5f * 49.0f;
  float iy = (yr + 1.0f) * 0.5f * 49.0f;
  float x0 = floorf(ix), y0 = floorf(iy);
  const float* src = lig_comb + (b * 2 + f) * NPIX;
  float acc = 0.0f;
  for (int dy = 0; dy < 2; ++dy)
    for (int dx = 0; dx < 2; ++dx) {
      float xc = x0 + dx, yc = y0 + dy;
      float w = (1.0f - fabsf(ix - xc)) * (1.0f - fabsf(iy - yc));
      bool valid = (xc >= 0.0f) && (xc < 50.0f) && (yc >= 0.0f) && (yc < 50.0f);
      int xi = (int)fminf(fmaxf(xc, 0.0f), 49.0f);
      int yi = (int)fminf(fmaxf(yc, 0.0f), 49.0f);
      acc += valid ? w * src[yi * L + xi] : 0.0f;
    }
  rot[t] = acc;
}

// ---------------- forward rfft2 of 50x50-supported image in 100x100 --------
// dst[img][m*51+k], m in [0,100), k in [0,51)
__global__ __launch_bounds__(256) void k_fwd_rec(
    const float* __restrict__ src, float2* __restrict__ dst) {
  __shared__ float img[NPIX];
  __shared__ float2 Arow[L * NFREQ];
  __shared__ float2 tw[NFULL];
  int tid = threadIdx.x;
  int im = blockIdx.x;
  if (tid < NFULL) {
    double th = 0.06283185307179586477 * tid;  // 2*pi/100
    tw[tid] = make_float2((float)cos(th), (float)sin(th));
  }
  for (int o = tid; o < NPIX; o += 256) img[o] = src[im * NPIX + o];
  __syncthreads();
  for (int o = tid; o < L * NFREQ; o += 256) {
    int r = o / NFREQ, k = o % NFREQ;
    float re = 0.f, ims = 0.f;
    int ti = 0;
    for (int c = 0; c < L; ++c) {
      float2 w = tw[ti];
      float v = img[r * L + c];
      re += v * w.x; ims -= v * w.y;
      ti += k; if (ti >= NFULL) ti -= NFULL;
    }
    Arow[o] = make_float2(re, ims);
  }
  __syncthreads();
  for (int o = tid; o < SPEC; o += 256) {
    int m = o / NFREQ, k = o % NFREQ;
    float gre = 0.f, gim = 0.f;
    int ti = 0;
    for (int r = 0; r < L; ++r) {
      float2 w = tw[ti];
      float2 av = Arow[r * NFREQ + k];
      gre += av.x * w.x + av.y * w.y;   // A * e^{-i th}
      gim += av.y * w.x - av.x * w.y;
      ti += m; if (ti >= NFULL) ti -= NFULL;
    }
    dst[im * SPEC + o] = make_float2(gre, gim);
  }
}

// ---------------- per (angle,batch): forward FFT of both combined ligand
// channels, multiply with conj against F1, accumulate P; store k-major ------
__global__ __launch_bounds__(256) void k_fwd_prod(
    const float* __restrict__ rot, const float2* __restrict__ F1,
    float2* __restrict__ P) {
  __shared__ float img[NPIX];
  __shared__ float2 Arow[L * NFREQ];
  __shared__ float2 tw[NFULL];
  int tid = threadIdx.x;
  int ab = blockIdx.x;          // a*8 + b
  int b = ab % NB;
  if (tid < NFULL) {
    double th = 0.06283185307179586477 * tid;
    tw[tid] = make_float2((float)cos(th), (float)sin(th));
  }
  float pre[20], pim[20];
  for (int q = 0; q < 20; ++q) { pre[q] = 0.f; pim[q] = 0.f; }
  for (int f = 0; f < 2; ++f) {
    __syncthreads();
    for (int o = tid; o < NPIX; o += 256) img[o] = rot[(ab * 2 + f) * NPIX + o];
    __syncthreads();
    for (int o = tid; o < L * NFREQ; o += 256) {
      int r = o / NFREQ, k = o % NFREQ;
      float re = 0.f, ims = 0.f;
      int ti = 0;
      for (int c = 0; c < L; ++c) {
        float2 w = tw[ti];
        float v = img[r * L + c];
        re += v * w.x; ims -= v * w.y;
        ti += k; if (ti >= NFULL) ti -= NFULL;
      }
      Arow[o] = make_float2(re, ims);
    }
    __syncthreads();
    int q = 0;
    for (int o = tid; o < SPEC; o += 256, ++q) {
      int m = o / NFREQ, k = o % NFREQ;
      float gre = 0.f, gim = 0.f;
      int ti = 0;
      for (int r = 0; r < L; ++r) {
        float2 w = tw[ti];
        float2 av = Arow[r * NFREQ + k];
        gre += av.x * w.x + av.y * w.y;
        gim += av.y * w.x - av.x * w.y;
        ti += m; if (ti >= NFULL) ti -= NFULL;
      }
      float2 Fv = F1[(b * 2 + f) * SPEC + o];
      pre[q] += Fv.x * gre + Fv.y * gim;   // F * conj(G)
      pim[q] += Fv.y * gre - Fv.x * gim;
    }
  }
  int q = 0;
  for (int o = tid; o < SPEC; o += 256, ++q) {
    int m = o / NFREQ, k = o % NFREQ;
    P[(ab * NFREQ + k) * NFULL + m] = make_float2(pre[q], pim[q]);
  }
}

// ---------------- inverse transform (unnormalized) + fftshift + argmax -----
#define KCH 8
__global__ __launch_bounds__(256) void k_inv_argmax(
    const float2* __restrict__ P, float* __restrict__ pval,
    int* __restrict__ pidx) {
  __shared__ float2 T[NFULL * NFREQ];      // [r][k]
  __shared__ float2 Pc[KCH * NFULL];
  __shared__ float2 tw[NFULL];
  __shared__ float rv[256];
  __shared__ int ri[256];
  int tid = threadIdx.x;
  int ab = blockIdx.x;
  if (tid < NFULL) {
    double th = 0.06283185307179586477 * tid;
    tw[tid] = make_float2((float)cos(th), (float)sin(th));
  }
  for (int k0 = 0; k0 < NFREQ; k0 += KCH) {
    int kn = min(KCH, NFREQ - k0);
    __syncthreads();
    for (int t = tid; t < kn * NFULL; t += 256)
      Pc[t] = P[(ab * NFREQ + k0) * NFULL + t];
    __syncthreads();
    for (int t = tid; t < kn * NFULL; t += 256) {
      int kc = t / NFULL, r = t % NFULL;
      float re = 0.f, ims = 0.f;
      int ti = 0;
      const float2* pc = &Pc[kc * NFULL];
      for (int m = 0; m < NFULL; ++m) {
        float2 w = tw[ti];
        float2 pv = pc[m];
        re += pv.x * w.x - pv.y * w.y;    // P * e^{+i th}
        ims += pv.y * w.x + pv.x * w.y;
        ti += r; if (ti >= NFULL) ti -= NFULL;
      }
      T[r * NFREQ + k0 + kc] = make_float2(re, ims);
    }
  }
  __syncthreads();
  float best = -3.4e38f; int bidx = 0x7fffffff;
  for (int o = tid; o < NFULL * NFULL; o += 256) {
    int r = o / NFULL, c = o % NFULL;
    const float2* Tr = &T[r * NFREQ];
    float v = Tr[0].x + ((c & 1) ? -Tr[50].x : Tr[50].x);
    int ti = c;  // k=1 index = c
    for (int k = 1; k < 50; ++k) {
      float2 w = tw[ti];
      float2 tv = Tr[k];
      v += 2.0f * (tv.x * w.x - tv.y * w.y);  // 2*Re(T * e^{+i th})
      ti += c; if (ti >= NFULL) ti -= NFULL;
    }
    int xs_ = r + 50; if (xs_ >= NFULL) xs_ -= NFULL;
    int ys_ = c + 50; if (ys_ >= NFULL) ys_ -= NFULL;
    int flat = xs_ * NFULL + ys_;
    if (v > best || (v == best && flat < bidx)) { best = v; bidx = flat; }
  }
  rv[tid] = best; ri[tid] = bidx;
  __syncthreads();
  for (int s = 128; s > 0; s >>= 1) {
    if (tid < s) {
      float ov = rv[tid + s]; int oi = ri[tid + s];
      if (ov > rv[tid] || (ov == rv[tid] && oi < ri[tid])) { rv[tid] = ov; ri[tid] = oi; }
    }
    __syncthreads();
  }
  if (tid == 0) { pval[ab] = rv[0]; pidx[ab] = (ab / NB) * 10000 + ri[0]; }
}

// ---------------- final per-batch reduction over 120 angles ----------------
__global__ void k_final(const float* __restrict__ pval,
                        const int* __restrict__ pidx, float* __restrict__ out) {
  int b = threadIdx.x;
  if (b >= NB) return;
  float best = -3.4e38f; int bidx = 0x7fffffff;
  for (int a = 0; a < NA; ++a) {
    float v = pval[a * NB + b]; int ix = pidx[a * NB + b];
    if (v > best || (v == best && ix < bidx)) { best = v; bidx = ix; }
  }
  int a = bidx / 10000, rr = bidx % 10000, x = rr / NFULL, y = rr % NFULL;
  out[b] = a * ASTEP;
  out[NB + b * 2 + 0] = (float)(x - L);
  out[NB + b * 2 + 1] = (float)(y - L);
}

extern "C" void kernel_launch(void* const* d_in, const int* in_sizes, int n_in,
                              void* d_out, int out_size, void* d_ws, size_t ws_size,
                              hipStream_t stream) {
  const float* receptor = (const float*)d_in[0];
  const float* ligand   = (const float*)d_in[1];
  const float* conv_w   = (const float*)d_in[2];
  const float* conv_b   = (const float*)d_in[3];
  const float* scorer_w = (const float*)d_in[4];
  // scorer_b (d_in[5]) is argmax-invariant: unused.
  float* ws = (float*)d_ws;
  float* rec_feat = ws + OFF_REC;
  float* lig_comb = ws + OFF_LIG;
  float* rot      = ws + OFF_ROT;
  float2* F1      = (float2*)(ws + OFF_F1);
  float2* P       = (float2*)(ws + OFF_P);
  float* pval     = ws + OFF_PVAL;
  int*   pidx     = (int*)(ws + OFF_PIDX);
  float* out      = (float*)d_out;

  k_conv<<<(NB * NPIX + 255) / 256, 256, 0, stream>>>(
      receptor, ligand, conv_w, conv_b, scorer_w, rec_feat, lig_comb);
  k_fwd_rec<<<16, 256, 0, stream>>>(rec_feat, F1);
  k_rotate<<<(NA * NB * 2 * NPIX + 255) / 256, 256, 0, stream>>>(lig_comb, rot);
  k_fwd_prod<<<NA * NB, 256, 0, stream>>>(rot, F1, P);
  k_inv_argmax<<<NA * NB, 256, 0, stream>>>(P, pval, pidx);
  k_final<<<1, 64, 0, stream>>>(pval, pidx, out);
}

// Round 2
// 634.113 us; speedup vs baseline: 1.1898x; 1.1898x over previous
//
#include <hip/hip_runtime.h>

#define L 50
#define NA 120
#define NB 8
#define NPIX 2500        // 50*50
#define NFREQ 51
#define NFULL 100
#define SPEC 5100        // 100*51
#define ASTEP 0.026179938779914944f   // pi/120
#define PHI   0.06283185307179586f    // 2*pi/100

// workspace layout in floats
#define OFF_REC   0          // 8*2*2500  = 40000
#define OFF_LIG   40000      // 8*2*2500  = 40000
#define OFF_F1    80000      // 16*5100 float2 = 163200 floats
#define OFF_PVAL  243200     // 960
#define OFF_PIDX  244160     // 960 ints

// ---------------- conv 3x3 (SAME) + bias; ligand channels combined with
// scorer weights (linearity: rotate/FFT commute with the real combine) ------
__global__ __launch_bounds__(256) void k_conv(
    const float* __restrict__ rec, const float* __restrict__ lig,
    const float* __restrict__ cw, const float* __restrict__ cb,
    const float* __restrict__ sw,
    float* __restrict__ rec_feat, float* __restrict__ lig_comb) {
  int t = blockIdx.x * blockDim.x + threadIdx.x;
  if (t >= NB * NPIX) return;
  int b = t / NPIX, p = t % NPIX;
  int i = p / L, j = p % L;
  float r0 = cb[0], r1 = cb[1], l0 = cb[0], l1 = cb[1];
  for (int di = 0; di < 3; ++di) {
    int ii = i + di - 1;
    if (ii < 0 || ii >= L) continue;
    for (int dj = 0; dj < 3; ++dj) {
      int jj = j + dj - 1;
      if (jj < 0 || jj >= L) continue;
      float w0 = cw[di * 3 + dj], w1 = cw[9 + di * 3 + dj];
      float xv = rec[b * NPIX + ii * L + jj];
      float yv = lig[b * NPIX + ii * L + jj];
      r0 += w0 * xv; r1 += w1 * xv;
      l0 += w0 * yv; l1 += w1 * yv;
    }
  }
  rec_feat[(b * 2 + 0) * NPIX + p] = r0;
  rec_feat[(b * 2 + 1) * NPIX + p] = r1;
  lig_comb[(b * 2 + 0) * NPIX + p] = sw[0] * l0 + sw[1] * l1;
  lig_comb[(b * 2 + 1) * NPIX + p] = sw[2] * l0 + sw[3] * l1;
}

// ---------------- forward rfft2 of receptor channels (16 images) -----------
// dst[im][m*51+k]
__global__ __launch_bounds__(256) void k_fwd_rec(
    const float* __restrict__ src, float2* __restrict__ dst) {
  __shared__ float img[NPIX];
  __shared__ float2 Arow[L * NFREQ];
  __shared__ float2 tw[NFULL];
  int tid = threadIdx.x;
  int im = blockIdx.x;
  if (tid < NFULL) {
    double th = 0.06283185307179586477 * tid;
    tw[tid] = make_float2((float)cos(th), (float)sin(th));
  }
  for (int o = tid; o < NPIX; o += 256) img[o] = src[im * NPIX + o];
  __syncthreads();
  for (int o = tid; o < L * NFREQ; o += 256) {
    int r = o / NFREQ, k = o % NFREQ;
    float re = 0.f, ims = 0.f;
    int ti = 0;
    for (int c = 0; c < L; ++c) {
      float2 w = tw[ti];
      float v = img[r * L + c];
      re += v * w.x; ims -= v * w.y;
      ti += k; if (ti >= NFULL) ti -= NFULL;
    }
    Arow[o] = make_float2(re, ims);
  }
  __syncthreads();
  for (int o = tid; o < SPEC; o += 256) {
    int m = o / NFREQ, k = o % NFREQ;
    float gre = 0.f, gim = 0.f;
    int ti = 0;
    for (int r = 0; r < L; ++r) {
      float2 w = tw[ti];
      float2 av = Arow[r * NFREQ + k];
      gre += av.x * w.x + av.y * w.y;   // A * e^{-i th}
      gim += av.y * w.x - av.x * w.y;
      ti += m; if (ti >= NFULL) ti -= NFULL;
    }
    dst[im * SPEC + o] = make_float2(gre, gim);
  }
}

// ---------------- fused per-(angle,batch): rotate -> fwd rfft2 -> spectral
// product -> inverse -> argmax. All LDS reads are wave-broadcast; twiddles via
// register recurrence renormalized every 25 steps. ---------------------------
__global__ __launch_bounds__(256, 3) void k_dock(
    const float* __restrict__ lig_comb, const float2* __restrict__ F1,
    float* __restrict__ pval, int* __restrict__ pidx) {
  // union buffer: phase 1 {img(2500 f) + Arow[50][52] f2}, phase 2 {P[m][52]},
  // phase 3 {T[k][100]}  -- 5200 float2 = 41600 B
  __shared__ __align__(16) float2 buf[5200];
  __shared__ float rv[256];
  __shared__ int ri[256];
  float* img   = (float*)buf;        // 2500 floats (bytes 0..10000)
  float2* Arow = buf + 1250;         // [r][52], bytes 10000..30800
  float2* PT   = buf;                // phase 2/3

  const int tid = threadIdx.x;
  const int ab = blockIdx.x;
  const int a = ab / NB, b = ab % NB;
  float sa, ca;
  sincosf((float)a * ASTEP, &sa, &ca);

  const int kR  = tid % NFREQ;       // rowDFT: k        (tid<255)
  const int rcR = tid / NFREQ;       //         r-chunk
  const int mC  = tid % NFULL;       // colDFT: m | stage1: r | stage2: c
  const int kcC = tid / NFULL;       // chunk id         (tid<200)
  const int k0  = kcC * 26;          // k chunk: [0,26) or [26,52)

  float pre[26], pim[26];
#pragma unroll
  for (int i = 0; i < 26; ++i) { pre[i] = 0.f; pim[i] = 0.f; }

  for (int f = 0; f < 2; ++f) {
    __syncthreads();
    // ---- rotate ligand combined-channel f into img ----
    const float* src = lig_comb + (b * 2 + f) * NPIX;
    for (int o = tid; o < NPIX; o += 256) {
      int i = o / L, j = o % L;
      float gx = fmaf((float)j, 2.0f / 49.0f, -1.0f);
      float gy = fmaf((float)i, 2.0f / 49.0f, -1.0f);
      float ix = (ca * gx + sa * gy + 1.0f) * 24.5f;
      float iy = (ca * gy - sa * gx + 1.0f) * 24.5f;
      float x0 = floorf(ix), y0 = floorf(iy);
      float acc = 0.f;
#pragma unroll
      for (int dy = 0; dy < 2; ++dy)
#pragma unroll
        for (int dx = 0; dx < 2; ++dx) {
          float xc = x0 + dx, yc = y0 + dy;
          float w = (1.0f - fabsf(ix - xc)) * (1.0f - fabsf(iy - yc));
          bool valid = (xc >= 0.f) && (xc < 50.f) && (yc >= 0.f) && (yc < 50.f);
          int xi = (int)fminf(fmaxf(xc, 0.f), 49.f);
          int yi = (int)fminf(fmaxf(yc, 0.f), 49.f);
          acc += valid ? w * src[yi * L + xi] : 0.f;
        }
      img[o] = acc;
    }
    __syncthreads();

    // ---- rowDFT: Arow[r][k] = sum_c img[r][c] e^{-i*PHI*k*c} ----
    if (tid < 255) {
      const int rbase = rcR * 10;
      float are[10], aim[10];
#pragma unroll
      for (int i = 0; i < 10; ++i) { are[i] = 0.f; aim[i] = 0.f; }
      float stx, sty;
      sincosf(PHI * (float)kR, &sty, &stx);
      sty = -sty;
      for (int c0 = 0; c0 < 50; c0 += 25) {
        float wx, wy;
        { int t0 = (c0 * kR) % 100;
          sincosf(PHI * (float)t0, &wy, &wx); wy = -wy; }
        for (int cc = 0; cc < 25; ++cc) {
          const float* ic = img + rbase * L + (c0 + cc);
#pragma unroll
          for (int i = 0; i < 10; ++i) {
            float v = ic[i * L];
            are[i] = fmaf(v, wx, are[i]);
            aim[i] = fmaf(v, wy, aim[i]);
          }
          float nx = fmaf(wx, stx, -wy * sty);
          float ny = fmaf(wx, sty,  wy * stx);
          wx = nx; wy = ny;
        }
      }
#pragma unroll
      for (int i = 0; i < 10; ++i)
        Arow[(rbase + i) * 52 + kR] = make_float2(are[i], aim[i]);
    }
    if (tid < 50) Arow[tid * 52 + 51] = make_float2(0.f, 0.f);  // pad k=51
    __syncthreads();

    // ---- colDFT G[m][k] + product P += F1 * conj(G) (regs) ----
    if (tid < 200) {
      float gre[26], gim[26];
#pragma unroll
      for (int i = 0; i < 26; ++i) { gre[i] = 0.f; gim[i] = 0.f; }
      float stx, sty;
      sincosf(PHI * (float)mC, &sty, &stx);
      sty = -sty;
      for (int r0 = 0; r0 < 50; r0 += 25) {
        float wx, wy;
        { int t0 = (r0 * mC) % 100;
          sincosf(PHI * (float)t0, &wy, &wx); wy = -wy; }
        for (int rr = 0; rr < 25; ++rr) {
          const float4* ap = (const float4*)(Arow + (r0 + rr) * 52 + k0);
#pragma unroll
          for (int i = 0; i < 13; ++i) {
            float4 q = ap[i];
            gre[2*i]   = fmaf(q.x, wx, fmaf(-q.y, wy, gre[2*i]));
            gim[2*i]   = fmaf(q.x, wy, fmaf( q.y, wx, gim[2*i]));
            gre[2*i+1] = fmaf(q.z, wx, fmaf(-q.w, wy, gre[2*i+1]));
            gim[2*i+1] = fmaf(q.z, wy, fmaf( q.w, wx, gim[2*i+1]));
          }
          float nx = fmaf(wx, stx, -wy * sty);
          float ny = fmaf(wx, sty,  wy * stx);
          wx = nx; wy = ny;
        }
      }
      const float2* Fp = F1 + (b * 2 + f) * SPEC + mC * NFREQ + k0;
#pragma unroll
      for (int i = 0; i < 26; ++i) {
        if (k0 + i < NFREQ) {
          float2 Fv = Fp[i];
          pre[i] = fmaf(Fv.x, gre[i], fmaf( Fv.y, gim[i], pre[i]));
          pim[i] = fmaf(Fv.y, gre[i], fmaf(-Fv.x, gim[i], pim[i]));
        }
      }
    }
  } // f

  __syncthreads();   // all img/Arow consumers done; buf becomes P
  if (tid < 200) {
    float4* pp = (float4*)(PT + mC * 52 + k0);
#pragma unroll
    for (int i = 0; i < 13; ++i)
      pp[i] = make_float4(pre[2*i], pim[2*i], pre[2*i+1], pim[2*i+1]);
  }
  __syncthreads();

  // ---- inverse stage 1: T[r][k] = sum_m P[m][k] e^{+i*PHI*m*r} ----
  float tre[26], tim[26];
  if (tid < 200) {
#pragma unroll
    for (int i = 0; i < 26; ++i) { tre[i] = 0.f; tim[i] = 0.f; }
    float stx, sty;
    sincosf(PHI * (float)mC, &sty, &stx);   // step = e^{+i*PHI*r}
    for (int m0 = 0; m0 < 100; m0 += 25) {
      float wx, wy;
      { int t0 = (m0 * mC) % 100;
        sincosf(PHI * (float)t0, &wy, &wx); }
      for (int mm = 0; mm < 25; ++mm) {
        const float4* pp = (const float4*)(PT + (m0 + mm) * 52 + k0);
#pragma unroll
        for (int i = 0; i < 13; ++i) {
          float4 q = pp[i];
          tre[2*i]   = fmaf(q.x, wx, fmaf(-q.y, wy, tre[2*i]));
          tim[2*i]   = fmaf(q.x, wy, fmaf( q.y, wx, tim[2*i]));
          tre[2*i+1] = fmaf(q.z, wx, fmaf(-q.w, wy, tre[2*i+1]));
          tim[2*i+1] = fmaf(q.z, wy, fmaf( q.w, wx, tim[2*i+1]));
        }
        float nx = fmaf(wx, stx, -wy * sty);
        float ny = fmaf(wx, sty,  wy * stx);
        wx = nx; wy = ny;
      }
    }
  }
  __syncthreads();   // all P reads done; buf becomes T[k][r]
  if (tid < 200) {
#pragma unroll
    for (int i = 0; i < 26; ++i)
      PT[(k0 + i) * NFULL + mC] = make_float2(tre[i], tim[i]);
  }
  __syncthreads();

  // ---- inverse stage 2 (irfft over k) + fftshifted argmax ----
  float best = -3.4e38f;
  int bidx = 0x7fffffff;
  if (tid < 200) {
    const int c = mC;
    const int r0 = kcC * 50;
    float sc[50];
    float sgn = (c & 1) ? -1.f : 1.f;
    {
      const float2* T0  = PT + 0  * NFULL + r0;
      const float2* T50 = PT + 50 * NFULL + r0;
#pragma unroll
      for (int i = 0; i < 50; ++i)
        sc[i] = T0[i].x + sgn * T50[i].x;
    }
    float stx, sty;
    sincosf(PHI * (float)c, &sty, &stx);    // step = e^{+i*PHI*c}
    float wx = stx, wy = sty;               // w at k=1
    for (int k = 1; k < 50; ++k) {
      if (k == 25) {
        int t0 = (25 * c) % 100;
        sincosf(PHI * (float)t0, &wy, &wx);
      }
      float w2x = wx + wx, w2y = wy + wy;
      const float4* tp = (const float4*)(PT + k * NFULL + r0);
#pragma unroll
      for (int i = 0; i < 25; ++i) {
        float4 q = tp[i];
        sc[2*i]   = fmaf(q.x, w2x, fmaf(-q.y, w2y, sc[2*i]));
        sc[2*i+1] = fmaf(q.z, w2x, fmaf(-q.w, w2y, sc[2*i+1]));
      }
      float nx = fmaf(wx, stx, -wy * sty);
      float ny = fmaf(wx, sty,  wy * stx);
      wx = nx; wy = ny;
    }
#pragma unroll
    for (int i = 0; i < 50; ++i) {
      int r = r0 + i;
      int xs = r + 50; if (xs >= 100) xs -= 100;
      int ys = c + 50; if (ys >= 100) ys -= 100;
      int flat = xs * 100 + ys;
      if (sc[i] > best || (sc[i] == best && flat < bidx)) { best = sc[i]; bidx = flat; }
    }
  }
  rv[tid] = best; ri[tid] = bidx;
  __syncthreads();
  for (int s = 128; s > 0; s >>= 1) {
    if (tid < s) {
      float ov = rv[tid + s]; int oi = ri[tid + s];
      if (ov > rv[tid] || (ov == rv[tid] && oi < ri[tid])) { rv[tid] = ov; ri[tid] = oi; }
    }
    __syncthreads();
  }
  if (tid == 0) { pval[ab] = rv[0]; pidx[ab] = a * 10000 + ri[0]; }
}

// ---------------- final per-batch reduction over 120 angles ----------------
__global__ void k_final(const float* __restrict__ pval,
                        const int* __restrict__ pidx, float* __restrict__ out) {
  int b = threadIdx.x;
  if (b >= NB) return;
  float best = -3.4e38f; int bidx = 0x7fffffff;
  for (int a = 0; a < NA; ++a) {
    float v = pval[a * NB + b]; int ix = pidx[a * NB + b];
    if (v > best || (v == best && ix < bidx)) { best = v; bidx = ix; }
  }
  int a = bidx / 10000, rr = bidx % 10000, x = rr / NFULL, y = rr % NFULL;
  out[b] = a * ASTEP;
  out[NB + b * 2 + 0] = (float)(x - L);
  out[NB + b * 2 + 1] = (float)(y - L);
}

extern "C" void kernel_launch(void* const* d_in, const int* in_sizes, int n_in,
                              void* d_out, int out_size, void* d_ws, size_t ws_size,
                              hipStream_t stream) {
  const float* receptor = (const float*)d_in[0];
  const float* ligand   = (const float*)d_in[1];
  const float* conv_w   = (const float*)d_in[2];
  const float* conv_b   = (const float*)d_in[3];
  const float* scorer_w = (const float*)d_in[4];
  // scorer_b (d_in[5]) is argmax-invariant: unused.
  float* ws = (float*)d_ws;
  float* rec_feat = ws + OFF_REC;
  float* lig_comb = ws + OFF_LIG;
  float2* F1      = (float2*)(ws + OFF_F1);
  float* pval     = ws + OFF_PVAL;
  int*   pidx     = (int*)(ws + OFF_PIDX);
  float* out      = (float*)d_out;

  k_conv<<<(NB * NPIX + 255) / 256, 256, 0, stream>>>(
      receptor, ligand, conv_w, conv_b, scorer_w, rec_feat, lig_comb);
  k_fwd_rec<<<16, 256, 0, stream>>>(rec_feat, F1);
  k_dock<<<NA * NB, 256, 0, stream>>>(lig_comb, F1, pval, pidx);
  k_final<<<1, 64, 0, stream>>>(pval, pidx, out);
}

// Round 3
// 498.397 us; speedup vs baseline: 1.5138x; 1.2723x over previous
//
#include <hip/hip_runtime.h>

#define L 50
#define NA 120
#define NB 8
#define NPIX 2500        // 50*50
#define NFREQ 51
#define NFULL 100
#define SPEC 5100        // 100*51
#define ASTEP 0.026179938779914944f   // pi/120
#define PHI   0.06283185307179586f    // 2*pi/100

// workspace layout in floats
#define OFF_REC   0          // 8*2*2500  = 40000
#define OFF_LIG   40000      // 8*2*2500  = 40000
#define OFF_F1    80000      // 16*5100 float2 = 163200 floats
#define OFF_PVAL  243200     // 960
#define OFF_PIDX  244160     // 960 ints

// ---------------- conv 3x3 (SAME) + bias; ligand channels combined with
// scorer weights (linearity: rotate/FFT commute with the real combine) ------
__global__ __launch_bounds__(256) void k_conv(
    const float* __restrict__ rec, const float* __restrict__ lig,
    const float* __restrict__ cw, const float* __restrict__ cb,
    const float* __restrict__ sw,
    float* __restrict__ rec_feat, float* __restrict__ lig_comb) {
  int t = blockIdx.x * blockDim.x + threadIdx.x;
  if (t >= NB * NPIX) return;
  int b = t / NPIX, p = t % NPIX;
  int i = p / L, j = p % L;
  float r0 = cb[0], r1 = cb[1], l0 = cb[0], l1 = cb[1];
  for (int di = 0; di < 3; ++di) {
    int ii = i + di - 1;
    if (ii < 0 || ii >= L) continue;
    for (int dj = 0; dj < 3; ++dj) {
      int jj = j + dj - 1;
      if (jj < 0 || jj >= L) continue;
      float w0 = cw[di * 3 + dj], w1 = cw[9 + di * 3 + dj];
      float xv = rec[b * NPIX + ii * L + jj];
      float yv = lig[b * NPIX + ii * L + jj];
      r0 += w0 * xv; r1 += w1 * xv;
      l0 += w0 * yv; l1 += w1 * yv;
    }
  }
  rec_feat[(b * 2 + 0) * NPIX + p] = r0;
  rec_feat[(b * 2 + 1) * NPIX + p] = r1;
  lig_comb[(b * 2 + 0) * NPIX + p] = sw[0] * l0 + sw[1] * l1;
  lig_comb[(b * 2 + 1) * NPIX + p] = sw[2] * l0 + sw[3] * l1;
}

// ---------------- forward rfft2 of receptor channels (16 images) -----------
__global__ __launch_bounds__(256) void k_fwd_rec(
    const float* __restrict__ src, float2* __restrict__ dst) {
  __shared__ float img[NPIX];
  __shared__ float2 Arow[L * NFREQ];
  __shared__ float2 tw[NFULL];
  int tid = threadIdx.x;
  int im = blockIdx.x;
  if (tid < NFULL) {
    double th = 0.06283185307179586477 * tid;
    tw[tid] = make_float2((float)cos(th), (float)sin(th));
  }
  for (int o = tid; o < NPIX; o += 256) img[o] = src[im * NPIX + o];
  __syncthreads();
  for (int o = tid; o < L * NFREQ; o += 256) {
    int r = o / NFREQ, k = o % NFREQ;
    float re = 0.f, ims = 0.f;
    int ti = 0;
    for (int c = 0; c < L; ++c) {
      float2 w = tw[ti];
      float v = img[r * L + c];
      re += v * w.x; ims -= v * w.y;
      ti += k; if (ti >= NFULL) ti -= NFULL;
    }
    Arow[o] = make_float2(re, ims);
  }
  __syncthreads();
  for (int o = tid; o < SPEC; o += 256) {
    int m = o / NFREQ, k = o % NFREQ;
    float gre = 0.f, gim = 0.f;
    int ti = 0;
    for (int r = 0; r < L; ++r) {
      float2 w = tw[ti];
      float2 av = Arow[r * NFREQ + k];
      gre += av.x * w.x + av.y * w.y;   // A * e^{-i th}
      gim += av.y * w.x - av.x * w.y;
      ti += m; if (ti >= NFULL) ti -= NFULL;
    }
    dst[im * SPEC + o] = make_float2(gre, gim);
  }
}

// ---------------- fused per-(angle,batch): rotate -> fwd rfft2 -> spectral
// product (P in LDS) -> in-place inverse -> argmax. No register array > 25
// floats -> no scratch spill. LDS 63.2 KB -> 2 blocks/CU. --------------------
__global__ __launch_bounds__(256, 2) void k_dock(
    const float* __restrict__ lig_comb, const float2* __restrict__ F1,
    float* __restrict__ pval, int* __restrict__ pidx) {
  // sbuf floats: [0,10200) P[100][51] f2 | [10200,15300) Arow[50][51] f2
  //              [15300,15800) imgS[10][50] | rv/ri union over dead Arow
  __shared__ __align__(16) float sbuf[15800];
  float2* P    = (float2*)sbuf;
  float2* Arow = (float2*)(sbuf + 10200);
  float*  imgS = sbuf + 15300;
  float*  rv   = sbuf + 10200;
  int*    ri   = (int*)(sbuf + 10456);

  const int tid = threadIdx.x;
  const int ab = blockIdx.x;
  const int a = ab / NB, b = ab % NB;
  float sa, ca;
  sincosf((float)a * ASTEP, &sa, &ca);

  const int kR  = tid % 51;    // rowDFT: k
  const int rlR = tid / 51;    // rowDFT: local rows rlR, rlR+5
  const int mS  = tid % 100;   // colDFT m | stage1 r | stage2 c
  const int cS  = tid / 100;   // chunk selector (tid<200)

  for (int f = 0; f < 2; ++f) {
    const float* src = lig_comb + (b * 2 + f) * NPIX;
    for (int s = 0; s < 5; ++s) {
      __syncthreads();   // prev imgS readers / f=0 Arow readers done
      // ---- rotate strip rows [10s,10s+10) ----
      for (int o = tid; o < 500; o += 256) {
        int i = s * 10 + o / 50, j = o % 50;
        float gx = fmaf((float)j, 2.0f / 49.0f, -1.0f);
        float gy = fmaf((float)i, 2.0f / 49.0f, -1.0f);
        float ix = (ca * gx + sa * gy + 1.0f) * 24.5f;
        float iy = (ca * gy - sa * gx + 1.0f) * 24.5f;
        float x0 = floorf(ix), y0 = floorf(iy);
        float acc = 0.f;
#pragma unroll
        for (int dy = 0; dy < 2; ++dy)
#pragma unroll
          for (int dx = 0; dx < 2; ++dx) {
            float xc = x0 + dx, yc = y0 + dy;
            float w = (1.0f - fabsf(ix - xc)) * (1.0f - fabsf(iy - yc));
            bool valid = (xc >= 0.f) && (xc < 50.f) && (yc >= 0.f) && (yc < 50.f);
            int xi = (int)fminf(fmaxf(xc, 0.f), 49.f);
            int yi = (int)fminf(fmaxf(yc, 0.f), 49.f);
            acc += valid ? w * src[yi * L + xi] : 0.f;
          }
        imgS[o] = acc;
      }
      __syncthreads();
      // ---- rowDFT of this strip: Arow[r][k] = sum_c img[r][c] e^{-i k c} ----
      if (tid < 255) {
        float are0 = 0.f, aim0 = 0.f, are1 = 0.f, aim1 = 0.f;
        float stx, sty;
        sincosf(PHI * (float)kR, &sty, &stx);
        sty = -sty;
        const float* i0 = imgS + rlR * 50;
        const float* i1 = imgS + (rlR + 5) * 50;
        for (int c0 = 0; c0 < 50; c0 += 25) {
          float wx, wy;
          int t0 = (c0 * kR) % 100;
          sincosf(PHI * (float)t0, &wy, &wx); wy = -wy;
          for (int cc = 0; cc < 25; ++cc) {
            float v0 = i0[c0 + cc], v1 = i1[c0 + cc];
            are0 = fmaf(v0, wx, are0); aim0 = fmaf(v0, wy, aim0);
            are1 = fmaf(v1, wx, are1); aim1 = fmaf(v1, wy, aim1);
            float nx = fmaf(wx, stx, -wy * sty);
            float ny = fmaf(wx, sty,  wy * stx);
            wx = nx; wy = ny;
          }
        }
        int rbase = s * 10;
        Arow[(rbase + rlR) * 51 + kR]     = make_float2(are0, aim0);
        Arow[(rbase + rlR + 5) * 51 + kR] = make_float2(are1, aim1);
      }
    }
    __syncthreads();   // Arow complete
    // ---- colDFT + spectral product, accumulate into LDS P ----
    for (int p = 0; p < 2; ++p) {
      if (tid < 200) {
        int kc = cS + 2 * p;
        int k0 = kc * 13;
        float gre[13], gim[13];
#pragma unroll
        for (int i = 0; i < 13; ++i) { gre[i] = 0.f; gim[i] = 0.f; }
        float stx, sty;
        sincosf(PHI * (float)mS, &sty, &stx);
        sty = -sty;
        for (int r0 = 0; r0 < 50; r0 += 25) {
          float wx, wy;
          int t0 = (r0 * mS) % 100;
          sincosf(PHI * (float)t0, &wy, &wx); wy = -wy;
          for (int rr = 0; rr < 25; ++rr) {
            const float2* ap = Arow + (r0 + rr) * 51 + k0;
#pragma unroll
            for (int i = 0; i < 13; ++i) {
              float2 q = ap[i];   // kc==3,i==12 reads junk; discarded below
              gre[i] = fmaf(q.x, wx, fmaf(-q.y, wy, gre[i]));
              gim[i] = fmaf(q.x, wy, fmaf( q.y, wx, gim[i]));
            }
            float nx = fmaf(wx, stx, -wy * sty);
            float ny = fmaf(wx, sty,  wy * stx);
            wx = nx; wy = ny;
          }
        }
        const float2* Fp = F1 + (b * 2 + f) * SPEC + mS * 51 + k0;
        float2* dst = P + mS * 51 + k0;
#pragma unroll
        for (int i = 0; i < 13; ++i) {
          if (k0 + i < 51) {
            float2 Fv = Fp[i];
            float pr = fmaf(Fv.x, gre[i],  Fv.y * gim[i]);
            float pi = fmaf(Fv.y, gre[i], -Fv.x * gim[i]);
            if (f == 0) dst[i] = make_float2(pr, pi);
            else { float2 o = dst[i]; dst[i] = make_float2(o.x + pr, o.y + pi); }
          }
        }
      }
    }
  } // f

  __syncthreads();   // P complete

  // ---- inverse stage 1, IN-PLACE on column chunks of P:
  //      T[r][k] = sum_m P[m][k] e^{+i m r} ----
  for (int p = 0; p < 2; ++p) {
    int kc = cS + 2 * p, k0 = kc * 13;
    float tre[13], tim[13];
    if (tid < 200) {
#pragma unroll
      for (int i = 0; i < 13; ++i) { tre[i] = 0.f; tim[i] = 0.f; }
      float stx, sty;
      sincosf(PHI * (float)mS, &sty, &stx);   // step e^{+i*PHI*r}
      for (int m0 = 0; m0 < 100; m0 += 25) {
        float wx, wy;
        int t0 = (m0 * mS) % 100;
        sincosf(PHI * (float)t0, &wy, &wx);
        for (int mm = 0; mm < 25; ++mm) {
          const float2* pp = P + (m0 + mm) * 51 + k0;
#pragma unroll
          for (int i = 0; i < 13; ++i) {
            float2 q = pp[i];   // kc==3,i==12 junk; discarded
            tre[i] = fmaf(q.x, wx, fmaf(-q.y, wy, tre[i]));
            tim[i] = fmaf(q.x, wy, fmaf( q.y, wx, tim[i]));
          }
          float nx = fmaf(wx, stx, -wy * sty);
          float ny = fmaf(wx, sty,  wy * stx);
          wx = nx; wy = ny;
        }
      }
    }
    __syncthreads();   // all reads of these columns done
    if (tid < 200) {
#pragma unroll
      for (int i = 0; i < 13; ++i)
        if (k0 + i < 51) P[mS * 51 + k0 + i] = make_float2(tre[i], tim[i]);
    }
    __syncthreads();
  }

  // ---- inverse stage 2 (irfft over k) + fftshifted argmax ----
  float best = -3.4e38f;
  int bidx = 0x7fffffff;
  if (tid < 200) {
    const int c = mS;
    float sgn = (c & 1) ? -1.f : 1.f;
    float stx, sty;
    sincosf(PHI * (float)c, &sty, &stx);      // step e^{+i*PHI*c}
    for (int p = 0; p < 2; ++p) {
      int r0 = (cS + 2 * p) * 25;
      float sc[25];
#pragma unroll
      for (int i = 0; i < 25; ++i) {
        const float2* Tr = P + (r0 + i) * 51;
        sc[i] = Tr[0].x + sgn * Tr[50].x;
      }
      float wx = stx, wy = sty;               // w at k=1
      for (int k = 1; k < 50; ++k) {
        if (k == 25) {
          int t0 = (25 * c) % 100;
          sincosf(PHI * (float)t0, &wy, &wx);
        }
        float w2x = wx + wx, w2y = wy + wy;
#pragma unroll
        for (int i = 0; i < 25; ++i) {
          float2 q = P[(r0 + i) * 51 + k];
          sc[i] = fmaf(q.x, w2x, fmaf(-q.y, w2y, sc[i]));
        }
        float nx = fmaf(wx, stx, -wy * sty);
        float ny = fmaf(wx, sty,  wy * stx);
        wx = nx; wy = ny;
      }
#pragma unroll
      for (int i = 0; i < 25; ++i) {
        int r = r0 + i;
        int xs = r + 50; if (xs >= 100) xs -= 100;
        int ys = c + 50; if (ys >= 100) ys -= 100;
        int flat = xs * 100 + ys;
        if (sc[i] > best || (sc[i] == best && flat < bidx)) { best = sc[i]; bidx = flat; }
      }
    }
  }
  __syncthreads();   // P reads done; Arow region long dead -> rv/ri
  rv[tid] = best; ri[tid] = bidx;
  __syncthreads();
  for (int s = 128; s > 0; s >>= 1) {
    if (tid < s) {
      float ov = rv[tid + s]; int oi = ri[tid + s];
      if (ov > rv[tid] || (ov == rv[tid] && oi < ri[tid])) { rv[tid] = ov; ri[tid] = oi; }
    }
    __syncthreads();
  }
  if (tid == 0) { pval[ab] = rv[0]; pidx[ab] = a * 10000 + ri[0]; }
}

// ---------------- final per-batch reduction over 120 angles ----------------
__global__ void k_final(const float* __restrict__ pval,
                        const int* __restrict__ pidx, float* __restrict__ out) {
  int b = threadIdx.x;
  if (b >= NB) return;
  float best = -3.4e38f; int bidx = 0x7fffffff;
  for (int a = 0; a < NA; ++a) {
    float v = pval[a * NB + b]; int ix = pidx[a * NB + b];
    if (v > best || (v == best && ix < bidx)) { best = v; bidx = ix; }
  }
  int a = bidx / 10000, rr = bidx % 10000, x = rr / NFULL, y = rr % NFULL;
  out[b] = a * ASTEP;
  out[NB + b * 2 + 0] = (float)(x - L);
  out[NB + b * 2 + 1] = (float)(y - L);
}

extern "C" void kernel_launch(void* const* d_in, const int* in_sizes, int n_in,
                              void* d_out, int out_size, void* d_ws, size_t ws_size,
                              hipStream_t stream) {
  const float* receptor = (const float*)d_in[0];
  const float* ligand   = (const float*)d_in[1];
  const float* conv_w   = (const float*)d_in[2];
  const float* conv_b   = (const float*)d_in[3];
  const float* scorer_w = (const float*)d_in[4];
  // scorer_b (d_in[5]) is argmax-invariant: unused.
  float* ws = (float*)d_ws;
  float* rec_feat = ws + OFF_REC;
  float* lig_comb = ws + OFF_LIG;
  float2* F1      = (float2*)(ws + OFF_F1);
  float* pval     = ws + OFF_PVAL;
  int*   pidx     = (int*)(ws + OFF_PIDX);
  float* out      = (float*)d_out;

  k_conv<<<(NB * NPIX + 255) / 256, 256, 0, stream>>>(
      receptor, ligand, conv_w, conv_b, scorer_w, rec_feat, lig_comb);
  k_fwd_rec<<<16, 256, 0, stream>>>(rec_feat, F1);
  k_dock<<<NA * NB, 256, 0, stream>>>(lig_comb, F1, pval, pidx);
  k_final<<<1, 64, 0, stream>>>(pval, pidx, out);
}

// Round 4
// 400.721 us; speedup vs baseline: 1.8828x; 1.2438x over previous
//
#include <hip/hip_runtime.h>

#define L 50
#define NA 120
#define NB 8
#define NPIX 2500
#define NFREQ 51
#define NFULL 100
#define IST 52                 // padded inner stride (16B-aligned rows)
#define ISPEC (NFULL * IST)    // 5200 float2 per spectrum
#define ASTEP 0.026179938779914944f   // pi/120
#define PHI   0.06283185307179586f    // 2*pi/100

// workspace layout in floats
#define OFF_REC  0                    // 8*2*2500 = 40000
#define OFF_LIG  40000                // 40000
#define OFF_F1   80000                // 16 * 5200 f2 = 166400 floats
#define OFF_P    246400               // 960 * 10400 = 9984000 floats
#define OFF_PVAL 10230400             // 960
#define OFF_PIDX 10231360             // 960

#define CROT(wx, wy, sx, sy) { float nx_ = fmaf(wx, sx, -(wy) * (sy)); \
                               float ny_ = fmaf(wx, sy,  (wy) * (sx)); \
                               wx = nx_; wy = ny_; }

// ---------------- conv 3x3 (SAME) + bias; ligand channels combined with
// scorer weights (linearity: rotate/FFT commute with the real combine) ------
__global__ __launch_bounds__(256) void k_conv(
    const float* __restrict__ rec, const float* __restrict__ lig,
    const float* __restrict__ cw, const float* __restrict__ cb,
    const float* __restrict__ sw,
    float* __restrict__ rec_feat, float* __restrict__ lig_comb) {
  int t = blockIdx.x * blockDim.x + threadIdx.x;
  if (t >= NB * NPIX) return;
  int b = t / NPIX, p = t % NPIX;
  int i = p / L, j = p % L;
  float r0 = cb[0], r1 = cb[1], l0 = cb[0], l1 = cb[1];
  for (int di = 0; di < 3; ++di) {
    int ii = i + di - 1;
    if (ii < 0 || ii >= L) continue;
    for (int dj = 0; dj < 3; ++dj) {
      int jj = j + dj - 1;
      if (jj < 0 || jj >= L) continue;
      float w0 = cw[di * 3 + dj], w1 = cw[9 + di * 3 + dj];
      float xv = rec[b * NPIX + ii * L + jj];
      float yv = lig[b * NPIX + ii * L + jj];
      r0 += w0 * xv; r1 += w1 * xv;
      l0 += w0 * yv; l1 += w1 * yv;
    }
  }
  rec_feat[(b * 2 + 0) * NPIX + p] = r0;
  rec_feat[(b * 2 + 1) * NPIX + p] = r1;
  lig_comb[(b * 2 + 0) * NPIX + p] = sw[0] * l0 + sw[1] * l1;
  lig_comb[(b * 2 + 1) * NPIX + p] = sw[2] * l0 + sw[3] * l1;
}

// ---- rowDFT: Arow[r][k] = sum_c img[r][c] e^{-i*PHI*k*c}, thread (k, rg) ---
__device__ __forceinline__ void rowdft(const float* img, float2* Arow, int tid) {
  if (tid < 255) {
    const int kR = tid % 51, rgR = tid / 51;   // rows rgR + 5t, t<10
    float are[10], aim[10];
#pragma unroll
    for (int t = 0; t < 10; ++t) { are[t] = 0.f; aim[t] = 0.f; }
    float stx, sty;
    sincosf(PHI * (float)kR, &sty, &stx); sty = -sty;     // step e^{-i phi k}
    for (int half = 0; half < 2; ++half) {
      int u0 = half ? 6 : 0, u1 = half ? 13 : 6;
      float wx, wy;
      int t0 = half ? (24 * kR) % 100 : 0;
      sincosf(PHI * (float)t0, &wy, &wx); wy = -wy;
      for (int u = u0; u < u1; ++u) {
        float4 q[10];
#pragma unroll
        for (int t = 0; t < 10; ++t)
          q[t] = *(const float4*)(img + (rgR + 5 * t) * IST + 4 * u);
#pragma unroll
        for (int v = 0; v < 4; ++v) {
#pragma unroll
          for (int t = 0; t < 10; ++t) {
            float val = (v == 0) ? q[t].x : (v == 1) ? q[t].y : (v == 2) ? q[t].z : q[t].w;
            are[t] = fmaf(val, wx, are[t]);
            aim[t] = fmaf(val, wy, aim[t]);
          }
          CROT(wx, wy, stx, sty);
        }
      }
    }
#pragma unroll
    for (int t = 0; t < 10; ++t)
      Arow[(rgR + 5 * t) * IST + kR] = make_float2(are[t], aim[t]);
  }
}

// ---- colDFT radix-2: G[m]=E+O, G[m+50]=E-O over even/odd r (r<50) ---------
__device__ __forceinline__ void coldft(const float2* Arow, int mp, int k0,
                                       float* Ex, float* Ey, float* Ox, float* Oy) {
#pragma unroll
  for (int i = 0; i < 14; ++i) { Ex[i] = 0.f; Ey[i] = 0.f; Ox[i] = 0.f; Oy[i] = 0.f; }
  float stx, sty;
  sincosf(PHI * (float)((2 * mp) % 100), &sty, &stx); sty = -sty;  // e^{-2i phi m}
  { float wx = 1.f, wy = 0.f;
    for (int s = 0; s < 25; ++s) {
      const float2* ap = Arow + (2 * s) * IST + k0;
#pragma unroll
      for (int i = 0; i < 14; ++i) {
        float2 q = ap[i];
        Ex[i] = fmaf(q.x, wx, fmaf(-q.y, wy, Ex[i]));
        Ey[i] = fmaf(q.x, wy, fmaf( q.y, wx, Ey[i]));
      }
      CROT(wx, wy, stx, sty);
    } }
  { float wx, wy;
    sincosf(PHI * (float)mp, &wy, &wx); wy = -wy;                  // e^{-i phi m}
    for (int s = 0; s < 25; ++s) {
      const float2* ap = Arow + (2 * s + 1) * IST + k0;
#pragma unroll
      for (int i = 0; i < 14; ++i) {
        float2 q = ap[i];
        Ox[i] = fmaf(q.x, wx, fmaf(-q.y, wy, Ox[i]));
        Oy[i] = fmaf(q.x, wy, fmaf( q.y, wx, Oy[i]));
      }
      CROT(wx, wy, stx, sty);
    } }
}

// ---------------- forward rfft2 of receptor channels (16 images) -----------
__global__ __launch_bounds__(256, 3) void k_fwd_rec(
    const float* __restrict__ src, float2* __restrict__ F1w) {
  __shared__ __align__(16) float img[50 * IST];
  __shared__ __align__(16) float2 Arow[50 * IST + 8];
  const int tid = threadIdx.x, im = blockIdx.x;
  for (int o = tid; o < 50 * IST; o += 256) {
    int i = o / IST, j = o - i * IST;
    img[o] = (j < 50) ? src[im * NPIX + i * 50 + j] : 0.f;
  }
  __syncthreads();
  rowdft(img, Arow, tid);
  __syncthreads();
  if (tid < 200) {
    const int mp = tid % 50, kc = tid / 50;
    const int k0 = (kc < 2) ? kc * 14 : 28 + (kc - 2) * 12;
    const int CW = (kc < 2) ? 14 : 12;
    float Ex[14], Ey[14], Ox[14], Oy[14];
    coldft(Arow, mp, k0, Ex, Ey, Ox, Oy);
    float2* d0 = F1w + (size_t)im * ISPEC + mp * IST + k0;
    float2* d1 = d0 + 50 * IST;
#pragma unroll
    for (int i = 0; i < 14; ++i)
      if (i < CW && k0 + i < 51) {
        d0[i] = make_float2(Ex[i] + Ox[i], Ey[i] + Oy[i]);
        d1[i] = make_float2(Ex[i] - Ox[i], Ey[i] - Oy[i]);
      }
  }
}

// ---------------- per-(angle,batch): rotate -> rfft2 -> product -> P -------
__global__ __launch_bounds__(256, 3) void k_fwd_prod(
    const float* __restrict__ lig_comb, const float2* __restrict__ F1,
    float2* __restrict__ P) {
  __shared__ __align__(16) float img[50 * IST];
  __shared__ __align__(16) float2 Arow[50 * IST + 8];
  const int tid = threadIdx.x;
  const int ab = blockIdx.x, a = ab / NB, b = ab % NB;
  float sa, ca; sincosf((float)a * ASTEP, &sa, &ca);
  const int mp = tid % 50, kc = tid / 50;
  const int k0 = (kc < 2) ? kc * 14 : 28 + (kc - 2) * 12;
  const int CW = (kc < 2) ? 14 : 12;
  float2* Pab = P + (size_t)ab * ISPEC;

  for (int f = 0; f < 2; ++f) {
    // rotate ligand combined-channel f into img (pad cols -> 0)
    const float* src = lig_comb + (b * 2 + f) * NPIX;
    for (int o = tid; o < 50 * IST; o += 256) {
      int i = o / IST, j = o - i * IST;
      float acc = 0.f;
      if (j < 50) {
        float gx = fmaf((float)j, 2.0f / 49.0f, -1.0f);
        float gy = fmaf((float)i, 2.0f / 49.0f, -1.0f);
        float ix = (ca * gx + sa * gy + 1.0f) * 24.5f;
        float iy = (ca * gy - sa * gx + 1.0f) * 24.5f;
        float x0 = floorf(ix), y0 = floorf(iy);
#pragma unroll
        for (int dy = 0; dy < 2; ++dy)
#pragma unroll
          for (int dx = 0; dx < 2; ++dx) {
            float xc = x0 + dx, yc = y0 + dy;
            float w = (1.0f - fabsf(ix - xc)) * (1.0f - fabsf(iy - yc));
            bool valid = (xc >= 0.f) && (xc < 50.f) && (yc >= 0.f) && (yc < 50.f);
            int xi = (int)fminf(fmaxf(xc, 0.f), 49.f);
            int yi = (int)fminf(fmaxf(yc, 0.f), 49.f);
            acc += valid ? w * src[yi * L + xi] : 0.f;
          }
      }
      img[o] = acc;
    }
    __syncthreads();            // img ready; prior colDFT's Arow reads done
    rowdft(img, Arow, tid);
    __syncthreads();            // Arow ready
    if (tid < 200) {
      float Ex[14], Ey[14], Ox[14], Oy[14];
      coldft(Arow, mp, k0, Ex, Ey, Ox, Oy);
      const float2* Fa = F1 + (size_t)(b * 2 + f) * ISPEC + mp * IST + k0;
      const float2* Fb = Fa + 50 * IST;
      float2* d0 = Pab + mp * IST + k0;
      float2* d1 = d0 + 50 * IST;
#pragma unroll
      for (int i = 0; i < 14; ++i)
        if (i < CW && k0 + i < 51) {
          float gx0 = Ex[i] + Ox[i], gy0 = Ey[i] + Oy[i];
          float gx1 = Ex[i] - Ox[i], gy1 = Ey[i] - Oy[i];
          float2 Fv0 = Fa[i], Fv1 = Fb[i];
          float2 p0 = make_float2(fmaf(Fv0.x, gx0,  Fv0.y * gy0),
                                  fmaf(Fv0.y, gx0, -Fv0.x * gy0));
          float2 p1 = make_float2(fmaf(Fv1.x, gx1,  Fv1.y * gy1),
                                  fmaf(Fv1.y, gx1, -Fv1.x * gy1));
          if (f == 0) { d0[i] = p0; d1[i] = p1; }
          else {
            float2 o0 = d0[i], o1 = d1[i];
            d0[i] = make_float2(o0.x + p0.x, o0.y + p0.y);
            d1[i] = make_float2(o1.x + p1.x, o1.y + p1.y);
          }
        }
    }
  }
}

// ---------------- inverse (radix-2 both stages) + fftshift + argmax --------
__global__ __launch_bounds__(256, 3) void k_inv_argmax(
    const float2* __restrict__ P, float* __restrict__ pval,
    int* __restrict__ pidx) {
  __shared__ __align__(16) float2 Pl[ISPEC + 8];   // P then (transposed) T
  __shared__ float rv[256];
  __shared__ int ri[256];
  const int tid = threadIdx.x, ab = blockIdx.x;
  // bulk coalesced load of P
  { const float4* s4 = (const float4*)(P + (size_t)ab * ISPEC);
    float4* d4 = (float4*)Pl;
    for (int o = tid; o < ISPEC / 2; o += 256) d4[o] = s4[o]; }
  __syncthreads();

  // stage 1: T[r][k] = sum_m P[m][k] e^{+i*PHI*m*r}; radix-2 pairs (r, r+50)
  const int rp = tid % 50, kc = tid / 50;
  const int k0 = (kc < 2) ? kc * 14 : 28 + (kc - 2) * 12;
  const int CW = (kc < 2) ? 14 : 12;
  float Ex[14], Ey[14], Ox[14], Oy[14];
  if (tid < 200) {
#pragma unroll
    for (int i = 0; i < 14; ++i) { Ex[i] = 0.f; Ey[i] = 0.f; Ox[i] = 0.f; Oy[i] = 0.f; }
    float stx, sty;
    sincosf(PHI * (float)((2 * rp) % 100), &sty, &stx);   // step e^{+2i phi r}
    { float wx = 1.f, wy = 0.f;
      for (int s = 0; s < 50; ++s) {
        if (s == 25) { wx = (rp & 1) ? -1.f : 1.f; wy = 0.f; }   // exact renorm
        const float2* pp = Pl + (2 * s) * IST + k0;
#pragma unroll
        for (int i = 0; i < 14; ++i) {
          float2 q = pp[i];
          Ex[i] = fmaf(q.x, wx, fmaf(-q.y, wy, Ex[i]));
          Ey[i] = fmaf(q.x, wy, fmaf( q.y, wx, Ey[i]));
        }
        CROT(wx, wy, stx, sty);
      } }
    { float wx, wy;
      sincosf(PHI * (float)rp, &wy, &wx);                  // e^{+i phi r}
      for (int s = 0; s < 50; ++s) {
        if (s == 25) { int t0 = (51 * rp) % 100; sincosf(PHI * (float)t0, &wy, &wx); }
        const float2* pp = Pl + (2 * s + 1) * IST + k0;
#pragma unroll
        for (int i = 0; i < 14; ++i) {
          float2 q = pp[i];
          Ox[i] = fmaf(q.x, wx, fmaf(-q.y, wy, Ox[i]));
          Oy[i] = fmaf(q.x, wy, fmaf( q.y, wx, Oy[i]));
        }
        CROT(wx, wy, stx, sty);
      } }
  }
  __syncthreads();   // all P reads complete
  if (tid < 200) {
#pragma unroll
    for (int i = 0; i < 14; ++i)
      if (i < CW && k0 + i < 51) {
        int k = k0 + i;
        Pl[k * NFULL + rp]      = make_float2(Ex[i] + Ox[i], Ey[i] + Oy[i]);
        Pl[k * NFULL + rp + 50] = make_float2(Ex[i] - Ox[i], Ey[i] - Oy[i]);
      }
  }
  __syncthreads();   // T[k][r] ready (transposed)

  // stage 2: X[r][c] = T0 + (-1)^c T50 + 2*sum_{k=1..49} Re(T_k e^{+i k c});
  // radix-2 pairs (c, c+50) via even/odd k. Thread (cp, rc).
  float best = -3.4e38f;
  int bidx = 0x7fffffff;
  if (tid < 200) {
    const int cp = tid % 50, rc = tid / 50;
    const int r0 = (rc < 2) ? rc * 26 : 52 + (rc - 2) * 24;   // 16B-aligned
    const int RW = (rc < 2) ? 26 : 24;
    float e[26], o[26];
#pragma unroll
    for (int i = 0; i < 26; ++i) { e[i] = 0.f; o[i] = 0.f; }
    float stx, sty;
    sincosf(PHI * (float)((2 * cp) % 100), &sty, &stx);       // step e^{+2i phi c}
    { float wx = stx, wy = sty;                               // k=2 start
      for (int s = 1; s < 25; ++s) {
        const float2* tp = Pl + (2 * s) * NFULL + r0;
#pragma unroll
        for (int i = 0; i < 26; ++i) {
          float2 q = tp[i];
          e[i] = fmaf(q.x, wx, fmaf(-q.y, wy, e[i]));
        }
        CROT(wx, wy, stx, sty);
      } }
    { float wx, wy;
      sincosf(PHI * (float)cp, &wy, &wx);                     // k=1 start
      for (int s = 0; s < 25; ++s) {
        const float2* tp = Pl + (2 * s + 1) * NFULL + r0;
#pragma unroll
        for (int i = 0; i < 26; ++i) {
          float2 q = tp[i];
          o[i] = fmaf(q.x, wx, fmaf(-q.y, wy, o[i]));
        }
        CROT(wx, wy, stx, sty);
      } }
    float sgn = (cp & 1) ? -1.f : 1.f;
    const float2* T0  = Pl + r0;
    const float2* T50 = Pl + 50 * NFULL + r0;
    const int ys0 = cp + 50, ys1 = cp;   // shifted y for c=cp, c=cp+50
#pragma unroll
    for (int i = 0; i < 26; ++i)
      if (i < RW) {
        int r = r0 + i;
        float base = T0[i].x + sgn * T50[i].x;
        float X0 = fmaf(2.f, e[i] + o[i], base);   // c = cp
        float X1 = fmaf(2.f, e[i] - o[i], base);   // c = cp + 50
        int xs = r + 50; if (xs >= 100) xs -= 100;
        int f0 = xs * 100 + ys0, f1 = xs * 100 + ys1;
        if (X0 > best || (X0 == best && f0 < bidx)) { best = X0; bidx = f0; }
        if (X1 > best || (X1 == best && f1 < bidx)) { best = X1; bidx = f1; }
      }
  }
  rv[tid] = best; ri[tid] = bidx;
  __syncthreads();
  for (int s = 128; s > 0; s >>= 1) {
    if (tid < s) {
      float ov = rv[tid + s]; int oi = ri[tid + s];
      if (ov > rv[tid] || (ov == rv[tid] && oi < ri[tid])) { rv[tid] = ov; ri[tid] = oi; }
    }
    __syncthreads();
  }
  if (tid == 0) { pval[ab] = rv[0]; pidx[ab] = (ab / NB) * 10000 + ri[0]; }
}

// ---------------- final per-batch reduction over 120 angles ----------------
__global__ void k_final(const float* __restrict__ pval,
                        const int* __restrict__ pidx, float* __restrict__ out) {
  int b = threadIdx.x;
  if (b >= NB) return;
  float best = -3.4e38f; int bidx = 0x7fffffff;
  for (int a = 0; a < NA; ++a) {
    float v = pval[a * NB + b]; int ix = pidx[a * NB + b];
    if (v > best || (v == best && ix < bidx)) { best = v; bidx = ix; }
  }
  int a = bidx / 10000, rr = bidx % 10000, x = rr / NFULL, y = rr % NFULL;
  out[b] = a * ASTEP;
  out[NB + b * 2 + 0] = (float)(x - L);
  out[NB + b * 2 + 1] = (float)(y - L);
}

extern "C" void kernel_launch(void* const* d_in, const int* in_sizes, int n_in,
                              void* d_out, int out_size, void* d_ws, size_t ws_size,
                              hipStream_t stream) {
  const float* receptor = (const float*)d_in[0];
  const float* ligand   = (const float*)d_in[1];
  const float* conv_w   = (const float*)d_in[2];
  const float* conv_b   = (const float*)d_in[3];
  const float* scorer_w = (const float*)d_in[4];
  // scorer_b (d_in[5]) is argmax-invariant: unused.
  float* ws = (float*)d_ws;
  float* rec_feat = ws + OFF_REC;
  float* lig_comb = ws + OFF_LIG;
  float2* F1      = (float2*)(ws + OFF_F1);
  float2* P       = (float2*)(ws + OFF_P);
  float* pval     = ws + OFF_PVAL;
  int*   pidx     = (int*)(ws + OFF_PIDX);
  float* out      = (float*)d_out;

  k_conv<<<(NB * NPIX + 255) / 256, 256, 0, stream>>>(
      receptor, ligand, conv_w, conv_b, scorer_w, rec_feat, lig_comb);
  k_fwd_rec<<<16, 256, 0, stream>>>(rec_feat, F1);
  k_fwd_prod<<<NA * NB, 256, 0, stream>>>(lig_comb, F1, P);
  k_inv_argmax<<<NA * NB, 256, 0, stream>>>(P, pval, pidx);
  k_final<<<1, 64, 0, stream>>>(pval, pidx, out);
}